// Round 7
// baseline (3951.576 us; speedup 1.0000x reference)
//
#include <hip/hip_runtime.h>
#include <hip/hip_fp16.h>

#define N_NODES_C 1000000
#define N_ELEMS_C 4000000
#define N_ENDP_C  (2 * N_ELEMS_C)
#define TILE 1024
#define N_TILES ((N_NODES_C + TILE - 1) / TILE)   // 977
#define CSTRIDE 16                                 // ints; one counter per 64B line

struct Scalars {
    double S_kin;
    double L_sum;
    double S_Fext;
    double S_force;
    double S_mom;
    double S_neu;
    unsigned long long n_fd;
    unsigned long long n_fr;
    unsigned long long n_pin;
    int q_max_bits;
    int L_max_bits;
};

__device__ __forceinline__ double waveSumD(double v) {
    for (int off = 32; off > 0; off >>= 1) v += __shfl_down(v, off, 64);
    return v;
}
__device__ __forceinline__ float waveMaxF(float v) {
    for (int off = 32; off > 0; off >>= 1) v = fmaxf(v, __shfl_down(v, off, 64));
    return v;
}
__device__ __forceinline__ int waveSumI(int v) {
    for (int off = 32; off > 0; off >>= 1) v += __shfl_down(v, off, 64);
    return v;
}
__device__ __forceinline__ unsigned packH2(float a, float b) {
    return (unsigned)__half_as_ushort(__float2half(a)) |
           ((unsigned)__half_as_ushort(__float2half(b)) << 16);
}
__device__ __forceinline__ float lowH(unsigned u)  { return __half2float(__ushort_as_half((unsigned short)(u & 0xFFFFu))); }
__device__ __forceinline__ float highH(unsigned u) { return __half2float(__ushort_as_half((unsigned short)(u >> 16))); }

// ============ build kernels ============

// fire-and-forget histogram (line-strided counters) + element-stream scalars
__global__ __launch_bounds__(256) void hist_scalars_s(
    const int* __restrict__ conn,
    const float* __restrict__ elem_len,
    const float* __restrict__ load,
    int* __restrict__ counts,          // strided by CSTRIDE
    Scalars* __restrict__ sc)
{
    int e = blockIdx.x * blockDim.x + threadIdx.x;
    double lsum = 0.0;
    float qm = 0.0f, lm = 0.0f;
    if (e < N_ELEMS_C) {
        int2 ij = ((const int2*)conn)[e];
        atomicAdd(&counts[(size_t)ij.x * CSTRIDE], 1);
        atomicAdd(&counts[(size_t)ij.y * CSTRIDE], 1);
        float L = elem_len[e];
        float q0 = load[3 * (size_t)e + 0];
        float q1 = load[3 * (size_t)e + 1];
        float q2 = load[3 * (size_t)e + 2];
        lsum = (double)L;
        lm = L;
        qm = fmaxf(fmaxf(fabsf(q0), fabsf(q1)), fabsf(q2));
    }
    lsum = waveSumD(lsum);
    qm = waveMaxF(qm);
    lm = waveMaxF(lm);
    if ((threadIdx.x & 63) == 0) {
        atomicAdd(&sc->L_sum, lsum);
        atomicMax(&sc->q_max_bits, __float_as_int(qm));
        atomicMax(&sc->L_max_bits, __float_as_int(lm));
    }
}

// dense histogram (Tier B fallback)
__global__ __launch_bounds__(256) void hist_scalars(
    const int* __restrict__ conn,
    const float* __restrict__ elem_len,
    const float* __restrict__ load,
    int* __restrict__ counts,
    Scalars* __restrict__ sc)
{
    int e = blockIdx.x * blockDim.x + threadIdx.x;
    double lsum = 0.0;
    float qm = 0.0f, lm = 0.0f;
    if (e < N_ELEMS_C) {
        int2 ij = ((const int2*)conn)[e];
        atomicAdd(&counts[ij.x], 1);
        atomicAdd(&counts[ij.y], 1);
        float L = elem_len[e];
        float q0 = load[3 * (size_t)e + 0];
        float q1 = load[3 * (size_t)e + 1];
        float q2 = load[3 * (size_t)e + 2];
        lsum = (double)L;
        lm = L;
        qm = fmaxf(fmaxf(fabsf(q0), fabsf(q1)), fabsf(q2));
    }
    lsum = waveSumD(lsum);
    qm = waveMaxF(qm);
    lm = waveMaxF(lm);
    if ((threadIdx.x & 63) == 0) {
        atomicAdd(&sc->L_sum, lsum);
        atomicMax(&sc->q_max_bits, __float_as_int(qm));
        atomicMax(&sc->L_max_bits, __float_as_int(lm));
    }
}

// ============ scan kernels ============

__global__ __launch_bounds__(256) void tile_sum_s(
    const int* __restrict__ counts, int* __restrict__ tileSums)
{
    int tile = blockIdx.x;
    int base = tile * TILE;
    int s = 0;
    for (int k = threadIdx.x; k < TILE; k += 256) {
        int idx = base + k;
        s += (idx < N_NODES_C) ? counts[(size_t)idx * CSTRIDE] : 0;
    }
    s = waveSumI(s);
    __shared__ int sh[4];
    if ((threadIdx.x & 63) == 0) sh[threadIdx.x >> 6] = s;
    __syncthreads();
    if (threadIdx.x == 0) tileSums[tile] = sh[0] + sh[1] + sh[2] + sh[3];
}

__global__ __launch_bounds__(256) void tile_sum(
    const int* __restrict__ counts, int* __restrict__ tileSums)
{
    int tile = blockIdx.x;
    int base = tile * TILE;
    int s = 0;
    for (int k = threadIdx.x; k < TILE; k += 256) {
        int idx = base + k;
        s += (idx < N_NODES_C) ? counts[idx] : 0;
    }
    s = waveSumI(s);
    __shared__ int sh[4];
    if ((threadIdx.x & 63) == 0) sh[threadIdx.x >> 6] = s;
    __syncthreads();
    if (threadIdx.x == 0) tileSums[tile] = sh[0] + sh[1] + sh[2] + sh[3];
}

__global__ __launch_bounds__(1024) void scan_tiles(int* __restrict__ tileSums)
{
    __shared__ int sh[1024];
    int t = threadIdx.x;
    int v = (t < N_TILES) ? tileSums[t] : 0;
    sh[t] = v;
    __syncthreads();
    for (int s = 1; s < 1024; s <<= 1) {
        int a = (t >= s) ? sh[t - s] : 0;
        __syncthreads();
        sh[t] += a;
        __syncthreads();
    }
    if (t < N_TILES) tileSums[t] = sh[t] - v;   // exclusive over tiles
}

// INCLUSIVE scan counts(strided) -> cur(strided) end offsets
__global__ __launch_bounds__(256) void scan_incl_s(
    const int* __restrict__ counts, const int* __restrict__ tileSums,
    int* __restrict__ cur)
{
    int tile = blockIdx.x;
    int base = tile * TILE;
    int t = threadIdx.x;
    int i0 = base + t * 4;
    int c0 = (i0 + 0 < N_NODES_C) ? counts[(size_t)(i0 + 0) * CSTRIDE] : 0;
    int c1 = (i0 + 1 < N_NODES_C) ? counts[(size_t)(i0 + 1) * CSTRIDE] : 0;
    int c2 = (i0 + 2 < N_NODES_C) ? counts[(size_t)(i0 + 2) * CSTRIDE] : 0;
    int c3 = (i0 + 3 < N_NODES_C) ? counts[(size_t)(i0 + 3) * CSTRIDE] : 0;
    int tsum = c0 + c1 + c2 + c3;
    __shared__ int sh[256];
    sh[t] = tsum;
    __syncthreads();
    for (int s = 1; s < 256; s <<= 1) {
        int a = (t >= s) ? sh[t - s] : 0;
        __syncthreads();
        sh[t] += a;
        __syncthreads();
    }
    int run = tileSums[tile] + (sh[t] - tsum);
    run += c0; if (i0 + 0 < N_NODES_C) cur[(size_t)(i0 + 0) * CSTRIDE] = run;
    run += c1; if (i0 + 1 < N_NODES_C) cur[(size_t)(i0 + 1) * CSTRIDE] = run;
    run += c2; if (i0 + 2 < N_NODES_C) cur[(size_t)(i0 + 2) * CSTRIDE] = run;
    run += c3; if (i0 + 3 < N_NODES_C) cur[(size_t)(i0 + 3) * CSTRIDE] = run;
}

// EXCLUSIVE scan -> offsets (Tier B)
__global__ __launch_bounds__(256) void scan_within(
    const int* __restrict__ counts, const int* __restrict__ tileSums,
    int* __restrict__ offsets)
{
    int tile = blockIdx.x;
    int base = tile * TILE;
    int t = threadIdx.x;
    int i0 = base + t * 4;
    int c0 = (i0 + 0 < N_NODES_C) ? counts[i0 + 0] : 0;
    int c1 = (i0 + 1 < N_NODES_C) ? counts[i0 + 1] : 0;
    int c2 = (i0 + 2 < N_NODES_C) ? counts[i0 + 2] : 0;
    int c3 = (i0 + 3 < N_NODES_C) ? counts[i0 + 3] : 0;
    int tsum = c0 + c1 + c2 + c3;
    __shared__ int sh[256];
    sh[t] = tsum;
    __syncthreads();
    for (int s = 1; s < 256; s <<= 1) {
        int a = (t >= s) ? sh[t - s] : 0;
        __syncthreads();
        sh[t] += a;
        __syncthreads();
    }
    int run = tileSums[tile] + (sh[t] - tsum);
    if (i0 + 0 < N_NODES_C) offsets[i0 + 0] = run; run += c0;
    if (i0 + 1 < N_NODES_C) offsets[i0 + 1] = run; run += c1;
    if (i0 + 2 < N_NODES_C) offsets[i0 + 2] = run; run += c2;
    if (i0 + 3 < N_NODES_C) offsets[i0 + 3] = run;
}

// ============ Tier S16: element physics + direct CSR scatter (24B records) ============
// recA[pos] = {Fc0,Fc1,Fc2, half2(fe0,fe1)}  (Fc = +F side i, -F side j)
// recB[pos] = {half2(Mc0,Mc1), half2(Mc2,fe2)}  (Mc = M_own*y)
__global__ __launch_bounds__(256) void main_direct(
    const float* __restrict__ phi,
    const float* __restrict__ grad_ux,
    const float* __restrict__ grad_uz,
    const float* __restrict__ grad_phi,
    const float* __restrict__ prop_E,
    const float* __restrict__ prop_A,
    const float* __restrict__ prop_I22,
    const float* __restrict__ elem_len,
    const float* __restrict__ xhat,
    const float* __restrict__ load,
    const int*   __restrict__ conn,
    int* __restrict__ cur,             // strided end offsets, consumed via atomicSub
    float4* __restrict__ recA,
    uint2*  __restrict__ recB,
    Scalars* __restrict__ sc)
{
    int e = blockIdx.x * blockDim.x + threadIdx.x;
    double kin = 0.0;

    if (e < N_ELEMS_C) {
        int2 ij = ((const int2*)conn)[e];
        size_t i = (size_t)ij.x;
        size_t j = (size_t)ij.y;

        // claim CSR slots first; latency hides behind the gathers below
        int posi = atomicSub(&cur[i * CSTRIDE], 1) - 1;
        int posj = atomicSub(&cur[j * CSTRIDE], 1) - 1;

        size_t e3 = 3 * (size_t)e;
        float x0 = xhat[e3 + 0];
        float x1 = xhat[e3 + 1];
        float x2 = xhat[e3 + 2];
        float L  = elem_len[e];
        float E  = prop_E[e];
        float EA = E * prop_A[e];
        float EI = E * prop_I22[e];
        float q0 = load[e3 + 0];
        float q1 = load[e3 + 1];
        float q2 = load[e3 + 2];

        // local axes (matches _local_axes exactly)
        bool  par = fabsf(x1) > 0.99f;
        float r1 = par ? 0.0f : 1.0f;
        float r2 = par ? 1.0f : 0.0f;
        float z0 = x1 * r2 - x2 * r1;
        float z1 = -x0 * r2;
        float z2 =  x0 * r1;
        float zn = fmaxf(sqrtf(z0 * z0 + z1 * z1 + z2 * z2), 1e-8f);
        z0 /= zn; z1 /= zn; z2 /= zn;
        float y0 = z1 * x2 - z2 * x1;
        float y1 = z2 * x0 - z0 * x2;
        float y2 = z0 * x1 - z1 * x0;
        float yn = fmaxf(sqrtf(y0 * y0 + y1 * y1 + y2 * y2), 1e-8f);
        y0 /= yn; y1 /= yn; y2 /= yn;

        size_t i3 = 3 * i, j3 = 3 * j;
        float gux_i_ax = grad_ux[i3 + 0] * x0 + grad_ux[i3 + 1] * x1 + grad_ux[i3 + 2] * x2;
        float gux_j_ax = grad_ux[j3 + 0] * x0 + grad_ux[j3 + 1] * x1 + grad_ux[j3 + 2] * x2;
        float guz_i_ax = grad_uz[i3 + 0] * x0 + grad_uz[i3 + 1] * x1 + grad_uz[i3 + 2] * x2;
        float guz_j_ax = grad_uz[j3 + 0] * x0 + grad_uz[j3 + 1] * x1 + grad_uz[j3 + 2] * x2;
        float kap_i    = grad_phi[i3 + 0] * x0 + grad_phi[i3 + 1] * x1 + grad_phi[i3 + 2] * x2;
        float kap_j    = grad_phi[j3 + 0] * x0 + grad_phi[j3 + 1] * x1 + grad_phi[j3 + 2] * x2;

        float eps_i = x0 * gux_i_ax + x2 * guz_i_ax;
        float eps_j = x0 * gux_j_ax + x2 * guz_j_ax;
        float N_avg = 0.5f * EA * (eps_i + eps_j);
        float M_i = EI * kap_i;
        float M_j = EI * kap_j;
        float V = (M_j - M_i) / L;
        float F0 = N_avg * x0 + V * z0;
        float F1 = N_avg * x1 + V * z1;
        float F2 = N_avg * x2 + V * z2;
        float hl = 0.5f * L;
        float fe0 = q0 * hl, fe1 = q1 * hl, fe2 = q2 * hl;

        float wA = __uint_as_float(packH2(fe0, fe1));
        recA[posi] = make_float4( F0,  F1,  F2, wA);
        recB[posi] = make_uint2(packH2(M_i * y0, M_i * y1), packH2(M_i * y2, fe2));
        recA[posj] = make_float4(-F0, -F1, -F2, wA);
        recB[posj] = make_uint2(packH2(M_j * y0, M_j * y1), packH2(M_j * y2, fe2));

        float du_i = z0 * gux_i_ax + z2 * guz_i_ax;
        float du_j = z0 * gux_j_ax + z2 * guz_j_ax;
        float rki = phi[i] - du_i;
        float rkj = phi[j] - du_j;
        kin = (double)rki * (double)rki + (double)rkj * (double)rkj;
    }

    kin = waveSumD(kin);
    if ((threadIdx.x & 63) == 0) {
        atomicAdd(&sc->S_kin, kin);
    }
}

// Tier S16 node pass: sequential streaming over CSR records
__global__ __launch_bounds__(256) void node_stream(
    const float* __restrict__ bc_disp,
    const float* __restrict__ bc_rot,
    const int*   __restrict__ cur,    // strided; post-fill: start offsets
    const float4* __restrict__ recA,
    const uint2*  __restrict__ recB,
    Scalars* __restrict__ sc)
{
    int n = blockIdx.x * blockDim.x + threadIdx.x;
    double sFext = 0.0, sForce = 0.0, sMom = 0.0, sNeu = 0.0;
    bool fd = false, fr = false, pin = false;

    if (n < N_NODES_C) {
        float bd = bc_disp[n];
        float br = bc_rot[n];
        fd  = bd < 0.5f;
        fr  = br < 0.5f;
        pin = (bd > 0.5f) && (br < 0.5f);

        int beg = cur[(size_t)n * CSTRIDE];
        int end = (n == N_NODES_C - 1) ? N_ENDP_C : cur[(size_t)(n + 1) * CSTRIDE];

        float fi0 = 0.f, fi1 = 0.f, fi2 = 0.f;
        float m0 = 0.f, m1 = 0.f, m2 = 0.f;
        float fe0 = 0.f, fe1 = 0.f, fe2 = 0.f;
        for (int k = beg; k < end; ++k) {
            float4 a = recA[k];
            uint2  b = recB[k];
            fi0 += a.x; fi1 += a.y; fi2 += a.z;
            unsigned ua = __float_as_uint(a.w);
            fe0 += lowH(ua); fe1 += highH(ua);
            m0 += lowH(b.x); m1 += highH(b.x);
            m2 += lowH(b.y); fe2 += highH(b.y);
        }

        double fesq = (double)fe0 * fe0 + (double)fe1 * fe1 + (double)fe2 * fe2;
        double s0 = (double)(fi0 + fe0);
        double s1 = (double)(fi1 + fe1);
        double s2 = (double)(fi2 + fe2);
        double fsq = s0 * s0 + s1 * s1 + s2 * s2;
        double msq = (double)m0 * m0 + (double)m1 * m1 + (double)m2 * m2;

        if (fd)  { sFext = fesq; sForce = fsq; }
        if (fr)  { sMom = msq; }
        if (pin) { sNeu = msq; }
    }

    unsigned long long cfd  = __popcll(__ballot(fd));
    unsigned long long cfr  = __popcll(__ballot(fr));
    unsigned long long cpin = __popcll(__ballot(pin));

    sFext  = waveSumD(sFext);
    sForce = waveSumD(sForce);
    sMom   = waveSumD(sMom);
    sNeu   = waveSumD(sNeu);

    if ((threadIdx.x & 63) == 0) {
        atomicAdd(&sc->S_Fext,  sFext);
        atomicAdd(&sc->S_force, sForce);
        atomicAdd(&sc->S_mom,   sMom);
        atomicAdd(&sc->S_neu,   sNeu);
        atomicAdd(&sc->n_fd,  cfd);
        atomicAdd(&sc->n_fr,  cfr);
        atomicAdd(&sc->n_pin, cpin);
    }
}

// ============ Tier B kernels (R3 verified) ============

__global__ __launch_bounds__(256) void fill_csr(
    const int* __restrict__ conn,
    const int* __restrict__ offsets,
    int* __restrict__ counts,
    int* __restrict__ eidside)
{
    int e = blockIdx.x * blockDim.x + threadIdx.x;
    if (e >= N_ELEMS_C) return;
    int2 ij = ((const int2*)conn)[e];
    int oi = atomicSub(&counts[ij.x], 1) - 1;
    eidside[offsets[ij.x] + oi] = (e << 1);
    int oj = atomicSub(&counts[ij.y], 1) - 1;
    eidside[offsets[ij.y] + oj] = (e << 1) | 1;
}

__global__ __launch_bounds__(256) void node_reduce_csr(
    const float* __restrict__ phi,
    const float* __restrict__ grad_ux,
    const float* __restrict__ grad_uz,
    const float* __restrict__ grad_phi,
    const float* __restrict__ prop_E,
    const float* __restrict__ prop_A,
    const float* __restrict__ prop_I22,
    const float* __restrict__ elem_len,
    const float* __restrict__ xhat,
    const float* __restrict__ load,
    const int*   __restrict__ conn,
    const float* __restrict__ bc_disp,
    const float* __restrict__ bc_rot,
    const int*   __restrict__ offsets,
    const int*   __restrict__ eidside,
    Scalars* __restrict__ sc)
{
    int n = blockIdx.x * blockDim.x + threadIdx.x;
    double sFext = 0.0, sForce = 0.0, sMom = 0.0, sNeu = 0.0, kin = 0.0;
    bool fd = false, fr = false, pin = false;

    if (n < N_NODES_C) {
        float bd = bc_disp[n];
        float br = bc_rot[n];
        fd  = bd < 0.5f;
        fr  = br < 0.5f;
        pin = (bd > 0.5f) && (br < 0.5f);

        float phin = phi[n];
        size_t b3 = 3 * (size_t)n;
        float ux0 = grad_ux[b3 + 0], ux1 = grad_ux[b3 + 1], ux2 = grad_ux[b3 + 2];
        float uz0 = grad_uz[b3 + 0], uz1 = grad_uz[b3 + 1], uz2 = grad_uz[b3 + 2];
        float gp0 = grad_phi[b3 + 0], gp1 = grad_phi[b3 + 1], gp2 = grad_phi[b3 + 2];

        int beg = offsets[n];
        int end = (n == N_NODES_C - 1) ? N_ENDP_C : offsets[n + 1];

        float fi0 = 0.f, fi1 = 0.f, fi2 = 0.f;
        float m0 = 0.f, m1 = 0.f, m2 = 0.f;
        float fe0 = 0.f, fe1 = 0.f, fe2 = 0.f;

        for (int k = beg; k < end; ++k) {
            int es = eidside[k];
            int e  = es >> 1;
            int s  = es & 1;
            int2 c = ((const int2*)conn)[e];
            size_t other = (size_t)(s ? c.x : c.y);

            size_t e3 = 3 * (size_t)e;
            float x0 = xhat[e3 + 0];
            float x1 = xhat[e3 + 1];
            float x2 = xhat[e3 + 2];
            float L  = elem_len[e];
            float E  = prop_E[e];
            float EA = E * prop_A[e];
            float EI = E * prop_I22[e];
            float q0 = load[e3 + 0];
            float q1 = load[e3 + 1];
            float q2 = load[e3 + 2];

            bool  par = fabsf(x1) > 0.99f;
            float r1 = par ? 0.0f : 1.0f;
            float r2 = par ? 1.0f : 0.0f;
            float z0 = x1 * r2 - x2 * r1;
            float z1 = -x0 * r2;
            float z2 =  x0 * r1;
            float zn = fmaxf(sqrtf(z0 * z0 + z1 * z1 + z2 * z2), 1e-8f);
            z0 /= zn; z1 /= zn; z2 /= zn;
            float y0 = z1 * x2 - z2 * x1;
            float y1 = z2 * x0 - z0 * x2;
            float y2 = z0 * x1 - z1 * x0;
            float yn = fmaxf(sqrtf(y0 * y0 + y1 * y1 + y2 * y2), 1e-8f);
            y0 /= yn; y1 /= yn; y2 /= yn;

            float own_ux_ax = ux0 * x0 + ux1 * x1 + ux2 * x2;
            float own_uz_ax = uz0 * x0 + uz1 * x1 + uz2 * x2;
            float kap_own   = gp0 * x0 + gp1 * x1 + gp2 * x2;

            size_t o3 = 3 * other;
            float oth_ux_ax = grad_ux[o3 + 0] * x0 + grad_ux[o3 + 1] * x1 + grad_ux[o3 + 2] * x2;
            float oth_uz_ax = grad_uz[o3 + 0] * x0 + grad_uz[o3 + 1] * x1 + grad_uz[o3 + 2] * x2;
            float kap_oth   = grad_phi[o3 + 0] * x0 + grad_phi[o3 + 1] * x1 + grad_phi[o3 + 2] * x2;

            float eps_own = x0 * own_ux_ax + x2 * own_uz_ax;
            float eps_oth = x0 * oth_ux_ax + x2 * oth_uz_ax;
            float N_avg = 0.5f * EA * (eps_own + eps_oth);
            float M_own = EI * kap_own;
            float M_oth = EI * kap_oth;
            float Vz = (M_oth - M_own) / L;
            float t = s ? -1.0f : 1.0f;

            fi0 += t * N_avg * x0 + Vz * z0;
            fi1 += t * N_avg * x1 + Vz * z1;
            fi2 += t * N_avg * x2 + Vz * z2;
            m0  += M_own * y0;
            m1  += M_own * y1;
            m2  += M_own * y2;
            float hl = 0.5f * L;
            fe0 += q0 * hl;
            fe1 += q1 * hl;
            fe2 += q2 * hl;

            float du = z0 * own_ux_ax + z2 * own_uz_ax;
            float rk = phin - du;
            kin += (double)rk * (double)rk;
        }

        double fesq = (double)fe0 * fe0 + (double)fe1 * fe1 + (double)fe2 * fe2;
        double s0 = (double)(fi0 + fe0);
        double s1 = (double)(fi1 + fe1);
        double s2 = (double)(fi2 + fe2);
        double fsq = s0 * s0 + s1 * s1 + s2 * s2;
        double msq = (double)m0 * m0 + (double)m1 * m1 + (double)m2 * m2;

        if (fd)  { sFext = fesq; sForce = fsq; }
        if (fr)  { sMom = msq; }
        if (pin) { sNeu = msq; }
    }

    unsigned long long cfd  = __popcll(__ballot(fd));
    unsigned long long cfr  = __popcll(__ballot(fr));
    unsigned long long cpin = __popcll(__ballot(pin));

    sFext  = waveSumD(sFext);
    sForce = waveSumD(sForce);
    sMom   = waveSumD(sMom);
    sNeu   = waveSumD(sNeu);
    kin    = waveSumD(kin);

    if ((threadIdx.x & 63) == 0) {
        atomicAdd(&sc->S_Fext,  sFext);
        atomicAdd(&sc->S_force, sForce);
        atomicAdd(&sc->S_mom,   sMom);
        atomicAdd(&sc->S_neu,   sNeu);
        atomicAdd(&sc->S_kin,   kin);
        atomicAdd(&sc->n_fd,  cfd);
        atomicAdd(&sc->n_fr,  cfr);
        atomicAdd(&sc->n_pin, cpin);
    }
}

// ============ finalize ============

__global__ void finalize_kernel(const Scalars* __restrict__ sc, float* __restrict__ out)
{
    double n_fd = (double)(sc->n_fd > 0ull ? sc->n_fd : 1ull);
    double n_fr = (double)(sc->n_fr > 0ull ? sc->n_fr : 1ull);

    double F_char = sqrt(sc->S_Fext / (3.0 * n_fd));
    if (F_char < 1.0) F_char = 1.0;

    double q_max = (double)__int_as_float(sc->q_max_bits);
    if (q_max < 1.0) q_max = 1.0;
    double L_max = (double)__int_as_float(sc->L_max_bits);
    double M_char = q_max * L_max * sc->L_sum / 8.0;
    if (M_char < 1.0) M_char = 1.0;

    double L_force  = sc->S_force / (3.0 * n_fd) / (F_char * F_char);
    double L_moment = sc->S_mom   / (3.0 * n_fr) / (M_char * M_char);
    double L_neu = 0.0;
    if (sc->n_pin > 0ull) {
        L_neu = sc->S_neu / (3.0 * (double)sc->n_pin) / (M_char * M_char);
    }
    double L_kin = 0.5 * sc->S_kin / (double)N_ELEMS_C;

    out[0] = (float)(1.0 * L_force + 1.0 * L_moment + 1.0 * L_neu + 0.1 * L_kin);
}

// ============ host ============

extern "C" void kernel_launch(void* const* d_in, const int* in_sizes, int n_in,
                              void* d_out, int out_size, void* d_ws, size_t ws_size,
                              hipStream_t stream) {
    const float* phi       = (const float*)d_in[0];
    const float* grad_ux   = (const float*)d_in[1];
    const float* grad_uz   = (const float*)d_in[2];
    const float* grad_phi  = (const float*)d_in[3];
    const float* prop_E    = (const float*)d_in[4];
    const float* prop_A    = (const float*)d_in[5];
    const float* prop_I22  = (const float*)d_in[6];
    const float* elem_len  = (const float*)d_in[7];
    const float* elem_dir  = (const float*)d_in[8];
    const float* elem_load = (const float*)d_in[9];
    const float* bc_disp   = (const float*)d_in[10];
    const float* bc_rot    = (const float*)d_in[11];
    const int*   conn      = (const int*)d_in[12];

    const size_t szSc    = 128;
    const size_t szCurS  = (size_t)N_NODES_C * 4 * CSTRIDE;  // 64 MB strided
    const size_t szTiles = 4096;
    const size_t szRecA  = (size_t)N_ENDP_C * 16;            // 128 MB
    const size_t szRecB  = (size_t)N_ENDP_C * 8;             //  64 MB
    const size_t szNode  = (size_t)N_NODES_C * 4;            //   4 MB
    const size_t szEid   = (size_t)N_ENDP_C * 4;             //  32 MB

    const size_t needS16 = szSc + szCurS + szTiles + szRecA + szRecB;   // 256,004,224
    const size_t needB   = szNode + szSc + szNode + szTiles + szEid;    // ~40.0 MB

    const int egrid = (N_ELEMS_C + 255) / 256;
    const int ngrid = (N_NODES_C + 255) / 256;

    if (ws_size >= needS16) {
        // ---- Tier S16: line-strided counters, 24B records ----
        char* p = (char*)d_ws;
        Scalars* sc   = (Scalars*)p;  p += szSc;
        int* cur      = (int*)p;      p += szCurS;
        int* tileSums = (int*)p;      p += szTiles;
        float4* recA  = (float4*)p;   p += szRecA;
        uint2*  recB  = (uint2*)p;
        int* counts   = (int*)recA;   // aliased: dead once scan_incl_s has produced cur

        hipMemsetAsync(sc, 0, szSc, stream);
        hipMemsetAsync(counts, 0, szCurS, stream);

        hist_scalars_s<<<egrid, 256, 0, stream>>>(conn, elem_len, elem_load, counts, sc);
        tile_sum_s<<<N_TILES, 256, 0, stream>>>(counts, tileSums);
        scan_tiles<<<1, 1024, 0, stream>>>(tileSums);
        scan_incl_s<<<N_TILES, 256, 0, stream>>>(counts, tileSums, cur);
        main_direct<<<egrid, 256, 0, stream>>>(
            phi, grad_ux, grad_uz, grad_phi,
            prop_E, prop_A, prop_I22, elem_len, elem_dir, elem_load, conn,
            cur, recA, recB, sc);
        node_stream<<<ngrid, 256, 0, stream>>>(
            bc_disp, bc_rot, cur, recA, recB, sc);
        finalize_kernel<<<1, 1, 0, stream>>>(sc, (float*)d_out);
    } else {
        // ---- Tier B (R3 verified) ----
        char* p = (char*)d_ws;
        int* counts   = (int*)p;      p += szNode;
        Scalars* sc   = (Scalars*)p;  p += szSc;
        int* offsets  = (int*)p;      p += szNode;
        int* tileSums = (int*)p;      p += szTiles;
        int* eidside  = (int*)p;

        hipMemsetAsync(counts, 0, szNode + szSc, stream);
        hist_scalars<<<egrid, 256, 0, stream>>>(conn, elem_len, elem_load, counts, sc);
        tile_sum<<<N_TILES, 256, 0, stream>>>(counts, tileSums);
        scan_tiles<<<1, 1024, 0, stream>>>(tileSums);
        scan_within<<<N_TILES, 256, 0, stream>>>(counts, tileSums, offsets);
        fill_csr<<<egrid, 256, 0, stream>>>(conn, offsets, counts, eidside);
        node_reduce_csr<<<ngrid, 256, 0, stream>>>(
            phi, grad_ux, grad_uz, grad_phi,
            prop_E, prop_A, prop_I22, elem_len, elem_dir, elem_load, conn,
            bc_disp, bc_rot, offsets, eidside, sc);
        finalize_kernel<<<1, 1, 0, stream>>>(sc, (float*)d_out);
    }
}

// Round 8
// 2694.585 us; speedup vs baseline: 1.4665x; 1.4665x over previous
//
#include <hip/hip_runtime.h>
#include <hip/hip_fp16.h>

#define N_NODES_C 1000000
#define N_ELEMS_C 4000000
#define N_ENDP_C  (2 * N_ELEMS_C)
#define TILE 1024
#define N_TILES ((N_NODES_C + TILE - 1) / TILE)   // 977
#define HIST_EPT 8
#define MAIN_EPT 4

struct Scalars {
    double S_kin;
    double L_sum;
    double S_Fext;
    double S_force;
    double S_mom;
    double S_neu;
    unsigned long long n_fd;
    unsigned long long n_fr;
    unsigned long long n_pin;
    int q_max_bits;
    int L_max_bits;
};

__device__ __forceinline__ double waveSumD(double v) {
    for (int off = 32; off > 0; off >>= 1) v += __shfl_down(v, off, 64);
    return v;
}
__device__ __forceinline__ float waveMaxF(float v) {
    for (int off = 32; off > 0; off >>= 1) v = fmaxf(v, __shfl_down(v, off, 64));
    return v;
}
__device__ __forceinline__ int waveSumI(int v) {
    for (int off = 32; off > 0; off >>= 1) v += __shfl_down(v, off, 64);
    return v;
}
__device__ __forceinline__ unsigned packH2(float a, float b) {
    return (unsigned)__half_as_ushort(__float2half(a)) |
           ((unsigned)__half_as_ushort(__float2half(b)) << 16);
}
__device__ __forceinline__ float lowH(unsigned u)  { return __half2float(__ushort_as_half((unsigned short)(u & 0xFFFFu))); }
__device__ __forceinline__ float highH(unsigned u) { return __half2float(__ushort_as_half((unsigned short)(u >> 16))); }

// ============ build kernels ============

// coarsened fire-and-forget histogram (16 atomics in flight/thread) + scalars
__global__ __launch_bounds__(256) void hist_scalars_c(
    const int* __restrict__ conn,
    const float* __restrict__ elem_len,
    const float* __restrict__ load,
    int* __restrict__ counts,
    Scalars* __restrict__ sc)
{
    int base = blockIdx.x * (256 * HIST_EPT) + threadIdx.x;
    double lsum = 0.0;
    float qm = 0.0f, lm = 0.0f;

    int2 ij[HIST_EPT];
    bool valid[HIST_EPT];
#pragma unroll
    for (int k = 0; k < HIST_EPT; ++k) {
        int e = base + k * 256;
        valid[k] = (e < N_ELEMS_C);
        if (valid[k]) ij[k] = ((const int2*)conn)[e];
    }
#pragma unroll
    for (int k = 0; k < HIST_EPT; ++k) {
        if (valid[k]) {
            atomicAdd(&counts[ij[k].x], 1);
            atomicAdd(&counts[ij[k].y], 1);
        }
    }
#pragma unroll
    for (int k = 0; k < HIST_EPT; ++k) {
        int e = base + k * 256;
        if (valid[k]) {
            float L = elem_len[e];
            float q0 = load[3 * (size_t)e + 0];
            float q1 = load[3 * (size_t)e + 1];
            float q2 = load[3 * (size_t)e + 2];
            lsum += (double)L;
            lm = fmaxf(lm, L);
            qm = fmaxf(qm, fmaxf(fmaxf(fabsf(q0), fabsf(q1)), fabsf(q2)));
        }
    }

    lsum = waveSumD(lsum);
    qm = waveMaxF(qm);
    lm = waveMaxF(lm);
    if ((threadIdx.x & 63) == 0) {
        atomicAdd(&sc->L_sum, lsum);
        atomicMax(&sc->q_max_bits, __float_as_int(qm));
        atomicMax(&sc->L_max_bits, __float_as_int(lm));
    }
}

// dense histogram (Tier B fallback)
__global__ __launch_bounds__(256) void hist_scalars(
    const int* __restrict__ conn,
    const float* __restrict__ elem_len,
    const float* __restrict__ load,
    int* __restrict__ counts,
    Scalars* __restrict__ sc)
{
    int e = blockIdx.x * blockDim.x + threadIdx.x;
    double lsum = 0.0;
    float qm = 0.0f, lm = 0.0f;
    if (e < N_ELEMS_C) {
        int2 ij = ((const int2*)conn)[e];
        atomicAdd(&counts[ij.x], 1);
        atomicAdd(&counts[ij.y], 1);
        float L = elem_len[e];
        float q0 = load[3 * (size_t)e + 0];
        float q1 = load[3 * (size_t)e + 1];
        float q2 = load[3 * (size_t)e + 2];
        lsum = (double)L;
        lm = L;
        qm = fmaxf(fmaxf(fabsf(q0), fabsf(q1)), fabsf(q2));
    }
    lsum = waveSumD(lsum);
    qm = waveMaxF(qm);
    lm = waveMaxF(lm);
    if ((threadIdx.x & 63) == 0) {
        atomicAdd(&sc->L_sum, lsum);
        atomicMax(&sc->q_max_bits, __float_as_int(qm));
        atomicMax(&sc->L_max_bits, __float_as_int(lm));
    }
}

// ============ scan kernels ============

__global__ __launch_bounds__(256) void tile_sum(
    const int* __restrict__ counts, int* __restrict__ tileSums)
{
    int tile = blockIdx.x;
    int base = tile * TILE;
    int s = 0;
    for (int k = threadIdx.x; k < TILE; k += 256) {
        int idx = base + k;
        s += (idx < N_NODES_C) ? counts[idx] : 0;
    }
    s = waveSumI(s);
    __shared__ int sh[4];
    if ((threadIdx.x & 63) == 0) sh[threadIdx.x >> 6] = s;
    __syncthreads();
    if (threadIdx.x == 0) tileSums[tile] = sh[0] + sh[1] + sh[2] + sh[3];
}

__global__ __launch_bounds__(1024) void scan_tiles(int* __restrict__ tileSums)
{
    __shared__ int sh[1024];
    int t = threadIdx.x;
    int v = (t < N_TILES) ? tileSums[t] : 0;
    sh[t] = v;
    __syncthreads();
    for (int s = 1; s < 1024; s <<= 1) {
        int a = (t >= s) ? sh[t - s] : 0;
        __syncthreads();
        sh[t] += a;
        __syncthreads();
    }
    if (t < N_TILES) tileSums[t] = sh[t] - v;   // exclusive over tiles
}

// INCLUSIVE scan -> cur (end offsets; decays to start offsets after fill)
__global__ __launch_bounds__(256) void scan_incl(
    const int* __restrict__ counts, const int* __restrict__ tileSums,
    int* __restrict__ cur)
{
    int tile = blockIdx.x;
    int base = tile * TILE;
    int t = threadIdx.x;
    int i0 = base + t * 4;
    int c0 = (i0 + 0 < N_NODES_C) ? counts[i0 + 0] : 0;
    int c1 = (i0 + 1 < N_NODES_C) ? counts[i0 + 1] : 0;
    int c2 = (i0 + 2 < N_NODES_C) ? counts[i0 + 2] : 0;
    int c3 = (i0 + 3 < N_NODES_C) ? counts[i0 + 3] : 0;
    int tsum = c0 + c1 + c2 + c3;
    __shared__ int sh[256];
    sh[t] = tsum;
    __syncthreads();
    for (int s = 1; s < 256; s <<= 1) {
        int a = (t >= s) ? sh[t - s] : 0;
        __syncthreads();
        sh[t] += a;
        __syncthreads();
    }
    int run = tileSums[tile] + (sh[t] - tsum);
    run += c0; if (i0 + 0 < N_NODES_C) cur[i0 + 0] = run;
    run += c1; if (i0 + 1 < N_NODES_C) cur[i0 + 1] = run;
    run += c2; if (i0 + 2 < N_NODES_C) cur[i0 + 2] = run;
    run += c3; if (i0 + 3 < N_NODES_C) cur[i0 + 3] = run;
}

// EXCLUSIVE scan -> offsets (Tier B)
__global__ __launch_bounds__(256) void scan_within(
    const int* __restrict__ counts, const int* __restrict__ tileSums,
    int* __restrict__ offsets)
{
    int tile = blockIdx.x;
    int base = tile * TILE;
    int t = threadIdx.x;
    int i0 = base + t * 4;
    int c0 = (i0 + 0 < N_NODES_C) ? counts[i0 + 0] : 0;
    int c1 = (i0 + 1 < N_NODES_C) ? counts[i0 + 1] : 0;
    int c2 = (i0 + 2 < N_NODES_C) ? counts[i0 + 2] : 0;
    int c3 = (i0 + 3 < N_NODES_C) ? counts[i0 + 3] : 0;
    int tsum = c0 + c1 + c2 + c3;
    __shared__ int sh[256];
    sh[t] = tsum;
    __syncthreads();
    for (int s = 1; s < 256; s <<= 1) {
        int a = (t >= s) ? sh[t - s] : 0;
        __syncthreads();
        sh[t] += a;
        __syncthreads();
    }
    int run = tileSums[tile] + (sh[t] - tsum);
    if (i0 + 0 < N_NODES_C) offsets[i0 + 0] = run; run += c0;
    if (i0 + 1 < N_NODES_C) offsets[i0 + 1] = run; run += c1;
    if (i0 + 2 < N_NODES_C) offsets[i0 + 2] = run; run += c2;
    if (i0 + 3 < N_NODES_C) offsets[i0 + 3] = run;
}

// ============ Tier S: coarsened element physics + direct CSR scatter ============
// recA[pos] = {Fc0,Fc1,Fc2, half2(fe0,fe1)}  (Fc = +F side i, -F side j)
// recB[pos] = {half2(Mc0,Mc1), half2(Mc2,fe2)}  (Mc = M_own*y)
__global__ __launch_bounds__(256) void main_direct_c(
    const float* __restrict__ phi,
    const float* __restrict__ grad_ux,
    const float* __restrict__ grad_uz,
    const float* __restrict__ grad_phi,
    const float* __restrict__ prop_E,
    const float* __restrict__ prop_A,
    const float* __restrict__ prop_I22,
    const float* __restrict__ elem_len,
    const float* __restrict__ xhat,
    const float* __restrict__ load,
    const int*   __restrict__ conn,
    int* __restrict__ cur,             // end offsets, consumed via atomicSub
    float4* __restrict__ recA,
    uint2*  __restrict__ recB,
    Scalars* __restrict__ sc)
{
    int base = blockIdx.x * (256 * MAIN_EPT) + threadIdx.x;
    double kin = 0.0;

    int2 ij[MAIN_EPT];
    int posi[MAIN_EPT], posj[MAIN_EPT];
    bool valid[MAIN_EPT];

#pragma unroll
    for (int k = 0; k < MAIN_EPT; ++k) {
        int e = base + k * 256;
        valid[k] = (e < N_ELEMS_C);
        if (valid[k]) ij[k] = ((const int2*)conn)[e];
    }
    // issue all 8 independent atomicSubs; single waitcnt covers them
#pragma unroll
    for (int k = 0; k < MAIN_EPT; ++k) {
        if (valid[k]) {
            posi[k] = atomicSub(&cur[ij[k].x], 1) - 1;
            posj[k] = atomicSub(&cur[ij[k].y], 1) - 1;
        }
    }

#pragma unroll
    for (int k = 0; k < MAIN_EPT; ++k) {
        if (!valid[k]) continue;
        int e = base + k * 256;
        size_t i = (size_t)ij[k].x;
        size_t j = (size_t)ij[k].y;

        size_t e3 = 3 * (size_t)e;
        float x0 = xhat[e3 + 0];
        float x1 = xhat[e3 + 1];
        float x2 = xhat[e3 + 2];
        float L  = elem_len[e];
        float E  = prop_E[e];
        float EA = E * prop_A[e];
        float EI = E * prop_I22[e];
        float q0 = load[e3 + 0];
        float q1 = load[e3 + 1];
        float q2 = load[e3 + 2];

        // local axes (matches _local_axes exactly)
        bool  par = fabsf(x1) > 0.99f;
        float r1 = par ? 0.0f : 1.0f;
        float r2 = par ? 1.0f : 0.0f;
        float z0 = x1 * r2 - x2 * r1;
        float z1 = -x0 * r2;
        float z2 =  x0 * r1;
        float zn = fmaxf(sqrtf(z0 * z0 + z1 * z1 + z2 * z2), 1e-8f);
        z0 /= zn; z1 /= zn; z2 /= zn;
        float y0 = z1 * x2 - z2 * x1;
        float y1 = z2 * x0 - z0 * x2;
        float y2 = z0 * x1 - z1 * x0;
        float yn = fmaxf(sqrtf(y0 * y0 + y1 * y1 + y2 * y2), 1e-8f);
        y0 /= yn; y1 /= yn; y2 /= yn;

        size_t i3 = 3 * i, j3 = 3 * j;
        float gux_i_ax = grad_ux[i3 + 0] * x0 + grad_ux[i3 + 1] * x1 + grad_ux[i3 + 2] * x2;
        float gux_j_ax = grad_ux[j3 + 0] * x0 + grad_ux[j3 + 1] * x1 + grad_ux[j3 + 2] * x2;
        float guz_i_ax = grad_uz[i3 + 0] * x0 + grad_uz[i3 + 1] * x1 + grad_uz[i3 + 2] * x2;
        float guz_j_ax = grad_uz[j3 + 0] * x0 + grad_uz[j3 + 1] * x1 + grad_uz[j3 + 2] * x2;
        float kap_i    = grad_phi[i3 + 0] * x0 + grad_phi[i3 + 1] * x1 + grad_phi[i3 + 2] * x2;
        float kap_j    = grad_phi[j3 + 0] * x0 + grad_phi[j3 + 1] * x1 + grad_phi[j3 + 2] * x2;

        float eps_i = x0 * gux_i_ax + x2 * guz_i_ax;
        float eps_j = x0 * gux_j_ax + x2 * guz_j_ax;
        float N_avg = 0.5f * EA * (eps_i + eps_j);
        float M_i = EI * kap_i;
        float M_j = EI * kap_j;
        float V = (M_j - M_i) / L;
        float F0 = N_avg * x0 + V * z0;
        float F1 = N_avg * x1 + V * z1;
        float F2 = N_avg * x2 + V * z2;
        float hl = 0.5f * L;
        float fe0 = q0 * hl, fe1 = q1 * hl, fe2 = q2 * hl;

        float wA = __uint_as_float(packH2(fe0, fe1));
        recA[posi[k]] = make_float4( F0,  F1,  F2, wA);
        recB[posi[k]] = make_uint2(packH2(M_i * y0, M_i * y1), packH2(M_i * y2, fe2));
        recA[posj[k]] = make_float4(-F0, -F1, -F2, wA);
        recB[posj[k]] = make_uint2(packH2(M_j * y0, M_j * y1), packH2(M_j * y2, fe2));

        float du_i = z0 * gux_i_ax + z2 * guz_i_ax;
        float du_j = z0 * gux_j_ax + z2 * guz_j_ax;
        float rki = phi[i] - du_i;
        float rkj = phi[j] - du_j;
        kin += (double)rki * (double)rki + (double)rkj * (double)rkj;
    }

    kin = waveSumD(kin);
    if ((threadIdx.x & 63) == 0) {
        atomicAdd(&sc->S_kin, kin);
    }
}

// Tier S node pass: sequential streaming over CSR records
__global__ __launch_bounds__(256) void node_stream(
    const float* __restrict__ bc_disp,
    const float* __restrict__ bc_rot,
    const int*   __restrict__ cur,    // post-fill: start offsets
    const float4* __restrict__ recA,
    const uint2*  __restrict__ recB,
    Scalars* __restrict__ sc)
{
    int n = blockIdx.x * blockDim.x + threadIdx.x;
    double sFext = 0.0, sForce = 0.0, sMom = 0.0, sNeu = 0.0;
    bool fd = false, fr = false, pin = false;

    if (n < N_NODES_C) {
        float bd = bc_disp[n];
        float br = bc_rot[n];
        fd  = bd < 0.5f;
        fr  = br < 0.5f;
        pin = (bd > 0.5f) && (br < 0.5f);

        int beg = cur[n];
        int end = (n == N_NODES_C - 1) ? N_ENDP_C : cur[n + 1];

        float fi0 = 0.f, fi1 = 0.f, fi2 = 0.f;
        float m0 = 0.f, m1 = 0.f, m2 = 0.f;
        float fe0 = 0.f, fe1 = 0.f, fe2 = 0.f;
        for (int k = beg; k < end; ++k) {
            float4 a = recA[k];
            uint2  b = recB[k];
            fi0 += a.x; fi1 += a.y; fi2 += a.z;
            unsigned ua = __float_as_uint(a.w);
            fe0 += lowH(ua); fe1 += highH(ua);
            m0 += lowH(b.x); m1 += highH(b.x);
            m2 += lowH(b.y); fe2 += highH(b.y);
        }

        double fesq = (double)fe0 * fe0 + (double)fe1 * fe1 + (double)fe2 * fe2;
        double s0 = (double)(fi0 + fe0);
        double s1 = (double)(fi1 + fe1);
        double s2 = (double)(fi2 + fe2);
        double fsq = s0 * s0 + s1 * s1 + s2 * s2;
        double msq = (double)m0 * m0 + (double)m1 * m1 + (double)m2 * m2;

        if (fd)  { sFext = fesq; sForce = fsq; }
        if (fr)  { sMom = msq; }
        if (pin) { sNeu = msq; }
    }

    unsigned long long cfd  = __popcll(__ballot(fd));
    unsigned long long cfr  = __popcll(__ballot(fr));
    unsigned long long cpin = __popcll(__ballot(pin));

    sFext  = waveSumD(sFext);
    sForce = waveSumD(sForce);
    sMom   = waveSumD(sMom);
    sNeu   = waveSumD(sNeu);

    if ((threadIdx.x & 63) == 0) {
        atomicAdd(&sc->S_Fext,  sFext);
        atomicAdd(&sc->S_force, sForce);
        atomicAdd(&sc->S_mom,   sMom);
        atomicAdd(&sc->S_neu,   sNeu);
        atomicAdd(&sc->n_fd,  cfd);
        atomicAdd(&sc->n_fr,  cfr);
        atomicAdd(&sc->n_pin, cpin);
    }
}

// ============ Tier B kernels (R3 verified) ============

__global__ __launch_bounds__(256) void fill_csr(
    const int* __restrict__ conn,
    const int* __restrict__ offsets,
    int* __restrict__ counts,
    int* __restrict__ eidside)
{
    int e = blockIdx.x * blockDim.x + threadIdx.x;
    if (e >= N_ELEMS_C) return;
    int2 ij = ((const int2*)conn)[e];
    int oi = atomicSub(&counts[ij.x], 1) - 1;
    eidside[offsets[ij.x] + oi] = (e << 1);
    int oj = atomicSub(&counts[ij.y], 1) - 1;
    eidside[offsets[ij.y] + oj] = (e << 1) | 1;
}

__global__ __launch_bounds__(256) void node_reduce_csr(
    const float* __restrict__ phi,
    const float* __restrict__ grad_ux,
    const float* __restrict__ grad_uz,
    const float* __restrict__ grad_phi,
    const float* __restrict__ prop_E,
    const float* __restrict__ prop_A,
    const float* __restrict__ prop_I22,
    const float* __restrict__ elem_len,
    const float* __restrict__ xhat,
    const float* __restrict__ load,
    const int*   __restrict__ conn,
    const float* __restrict__ bc_disp,
    const float* __restrict__ bc_rot,
    const int*   __restrict__ offsets,
    const int*   __restrict__ eidside,
    Scalars* __restrict__ sc)
{
    int n = blockIdx.x * blockDim.x + threadIdx.x;
    double sFext = 0.0, sForce = 0.0, sMom = 0.0, sNeu = 0.0, kin = 0.0;
    bool fd = false, fr = false, pin = false;

    if (n < N_NODES_C) {
        float bd = bc_disp[n];
        float br = bc_rot[n];
        fd  = bd < 0.5f;
        fr  = br < 0.5f;
        pin = (bd > 0.5f) && (br < 0.5f);

        float phin = phi[n];
        size_t b3 = 3 * (size_t)n;
        float ux0 = grad_ux[b3 + 0], ux1 = grad_ux[b3 + 1], ux2 = grad_ux[b3 + 2];
        float uz0 = grad_uz[b3 + 0], uz1 = grad_uz[b3 + 1], uz2 = grad_uz[b3 + 2];
        float gp0 = grad_phi[b3 + 0], gp1 = grad_phi[b3 + 1], gp2 = grad_phi[b3 + 2];

        int beg = offsets[n];
        int end = (n == N_NODES_C - 1) ? N_ENDP_C : offsets[n + 1];

        float fi0 = 0.f, fi1 = 0.f, fi2 = 0.f;
        float m0 = 0.f, m1 = 0.f, m2 = 0.f;
        float fe0 = 0.f, fe1 = 0.f, fe2 = 0.f;

        for (int k = beg; k < end; ++k) {
            int es = eidside[k];
            int e  = es >> 1;
            int s  = es & 1;
            int2 c = ((const int2*)conn)[e];
            size_t other = (size_t)(s ? c.x : c.y);

            size_t e3 = 3 * (size_t)e;
            float x0 = xhat[e3 + 0];
            float x1 = xhat[e3 + 1];
            float x2 = xhat[e3 + 2];
            float L  = elem_len[e];
            float E  = prop_E[e];
            float EA = E * prop_A[e];
            float EI = E * prop_I22[e];
            float q0 = load[e3 + 0];
            float q1 = load[e3 + 1];
            float q2 = load[e3 + 2];

            bool  par = fabsf(x1) > 0.99f;
            float r1 = par ? 0.0f : 1.0f;
            float r2 = par ? 1.0f : 0.0f;
            float z0 = x1 * r2 - x2 * r1;
            float z1 = -x0 * r2;
            float z2 =  x0 * r1;
            float zn = fmaxf(sqrtf(z0 * z0 + z1 * z1 + z2 * z2), 1e-8f);
            z0 /= zn; z1 /= zn; z2 /= zn;
            float y0 = z1 * x2 - z2 * x1;
            float y1 = z2 * x0 - z0 * x2;
            float y2 = z0 * x1 - z1 * x0;
            float yn = fmaxf(sqrtf(y0 * y0 + y1 * y1 + y2 * y2), 1e-8f);
            y0 /= yn; y1 /= yn; y2 /= yn;

            float own_ux_ax = ux0 * x0 + ux1 * x1 + ux2 * x2;
            float own_uz_ax = uz0 * x0 + uz1 * x1 + uz2 * x2;
            float kap_own   = gp0 * x0 + gp1 * x1 + gp2 * x2;

            size_t o3 = 3 * other;
            float oth_ux_ax = grad_ux[o3 + 0] * x0 + grad_ux[o3 + 1] * x1 + grad_ux[o3 + 2] * x2;
            float oth_uz_ax = grad_uz[o3 + 0] * x0 + grad_uz[o3 + 1] * x1 + grad_uz[o3 + 2] * x2;
            float kap_oth   = grad_phi[o3 + 0] * x0 + grad_phi[o3 + 1] * x1 + grad_phi[o3 + 2] * x2;

            float eps_own = x0 * own_ux_ax + x2 * own_uz_ax;
            float eps_oth = x0 * oth_ux_ax + x2 * oth_uz_ax;
            float N_avg = 0.5f * EA * (eps_own + eps_oth);
            float M_own = EI * kap_own;
            float M_oth = EI * kap_oth;
            float Vz = (M_oth - M_own) / L;
            float t = s ? -1.0f : 1.0f;

            fi0 += t * N_avg * x0 + Vz * z0;
            fi1 += t * N_avg * x1 + Vz * z1;
            fi2 += t * N_avg * x2 + Vz * z2;
            m0  += M_own * y0;
            m1  += M_own * y1;
            m2  += M_own * y2;
            float hl = 0.5f * L;
            fe0 += q0 * hl;
            fe1 += q1 * hl;
            fe2 += q2 * hl;

            float du = z0 * own_ux_ax + z2 * own_uz_ax;
            float rk = phin - du;
            kin += (double)rk * (double)rk;
        }

        double fesq = (double)fe0 * fe0 + (double)fe1 * fe1 + (double)fe2 * fe2;
        double s0 = (double)(fi0 + fe0);
        double s1 = (double)(fi1 + fe1);
        double s2 = (double)(fi2 + fe2);
        double fsq = s0 * s0 + s1 * s1 + s2 * s2;
        double msq = (double)m0 * m0 + (double)m1 * m1 + (double)m2 * m2;

        if (fd)  { sFext = fesq; sForce = fsq; }
        if (fr)  { sMom = msq; }
        if (pin) { sNeu = msq; }
    }

    unsigned long long cfd  = __popcll(__ballot(fd));
    unsigned long long cfr  = __popcll(__ballot(fr));
    unsigned long long cpin = __popcll(__ballot(pin));

    sFext  = waveSumD(sFext);
    sForce = waveSumD(sForce);
    sMom   = waveSumD(sMom);
    sNeu   = waveSumD(sNeu);
    kin    = waveSumD(kin);

    if ((threadIdx.x & 63) == 0) {
        atomicAdd(&sc->S_Fext,  sFext);
        atomicAdd(&sc->S_force, sForce);
        atomicAdd(&sc->S_mom,   sMom);
        atomicAdd(&sc->S_neu,   sNeu);
        atomicAdd(&sc->S_kin,   kin);
        atomicAdd(&sc->n_fd,  cfd);
        atomicAdd(&sc->n_fr,  cfr);
        atomicAdd(&sc->n_pin, cpin);
    }
}

// ============ finalize ============

__global__ void finalize_kernel(const Scalars* __restrict__ sc, float* __restrict__ out)
{
    double n_fd = (double)(sc->n_fd > 0ull ? sc->n_fd : 1ull);
    double n_fr = (double)(sc->n_fr > 0ull ? sc->n_fr : 1ull);

    double F_char = sqrt(sc->S_Fext / (3.0 * n_fd));
    if (F_char < 1.0) F_char = 1.0;

    double q_max = (double)__int_as_float(sc->q_max_bits);
    if (q_max < 1.0) q_max = 1.0;
    double L_max = (double)__int_as_float(sc->L_max_bits);
    double M_char = q_max * L_max * sc->L_sum / 8.0;
    if (M_char < 1.0) M_char = 1.0;

    double L_force  = sc->S_force / (3.0 * n_fd) / (F_char * F_char);
    double L_moment = sc->S_mom   / (3.0 * n_fr) / (M_char * M_char);
    double L_neu = 0.0;
    if (sc->n_pin > 0ull) {
        L_neu = sc->S_neu / (3.0 * (double)sc->n_pin) / (M_char * M_char);
    }
    double L_kin = 0.5 * sc->S_kin / (double)N_ELEMS_C;

    out[0] = (float)(1.0 * L_force + 1.0 * L_moment + 1.0 * L_neu + 0.1 * L_kin);
}

// ============ host ============

extern "C" void kernel_launch(void* const* d_in, const int* in_sizes, int n_in,
                              void* d_out, int out_size, void* d_ws, size_t ws_size,
                              hipStream_t stream) {
    const float* phi       = (const float*)d_in[0];
    const float* grad_ux   = (const float*)d_in[1];
    const float* grad_uz   = (const float*)d_in[2];
    const float* grad_phi  = (const float*)d_in[3];
    const float* prop_E    = (const float*)d_in[4];
    const float* prop_A    = (const float*)d_in[5];
    const float* prop_I22  = (const float*)d_in[6];
    const float* elem_len  = (const float*)d_in[7];
    const float* elem_dir  = (const float*)d_in[8];
    const float* elem_load = (const float*)d_in[9];
    const float* bc_disp   = (const float*)d_in[10];
    const float* bc_rot    = (const float*)d_in[11];
    const int*   conn      = (const int*)d_in[12];

    const size_t szSc    = 128;
    const size_t szNode  = (size_t)N_NODES_C * 4;   //   4 MB
    const size_t szTiles = 4096;
    const size_t szRecA  = (size_t)N_ENDP_C * 16;   // 128 MB
    const size_t szRecB  = (size_t)N_ENDP_C * 8;    //  64 MB
    const size_t szEid   = (size_t)N_ENDP_C * 4;    //  32 MB

    const size_t needS = szSc + szNode + szTiles + szRecA + szRecB;  // ~196 MB
    const size_t needB = szNode + szSc + szNode + szTiles + szEid;   //  ~40 MB

    const int egrid = (N_ELEMS_C + 255) / 256;
    const int ngrid = (N_NODES_C + 255) / 256;
    const int hgrid = (N_ELEMS_C + 256 * HIST_EPT - 1) / (256 * HIST_EPT);
    const int mgrid = (N_ELEMS_C + 256 * MAIN_EPT - 1) / (256 * MAIN_EPT);

    if (ws_size >= needS) {
        // ---- Tier S (coarsened): sc | cur | tiles | recA | recB; counts aliases recA ----
        char* p = (char*)d_ws;
        Scalars* sc   = (Scalars*)p;  p += szSc;
        int* cur      = (int*)p;      p += szNode;
        int* tileSums = (int*)p;      p += szTiles;
        float4* recA  = (float4*)p;   p += szRecA;
        uint2*  recB  = (uint2*)p;
        int* counts   = (int*)recA;   // aliased: dead once scan_incl has produced cur

        hipMemsetAsync(sc, 0, szSc, stream);
        hipMemsetAsync(counts, 0, szNode, stream);

        hist_scalars_c<<<hgrid, 256, 0, stream>>>(conn, elem_len, elem_load, counts, sc);
        tile_sum<<<N_TILES, 256, 0, stream>>>(counts, tileSums);
        scan_tiles<<<1, 1024, 0, stream>>>(tileSums);
        scan_incl<<<N_TILES, 256, 0, stream>>>(counts, tileSums, cur);
        main_direct_c<<<mgrid, 256, 0, stream>>>(
            phi, grad_ux, grad_uz, grad_phi,
            prop_E, prop_A, prop_I22, elem_len, elem_dir, elem_load, conn,
            cur, recA, recB, sc);
        node_stream<<<ngrid, 256, 0, stream>>>(
            bc_disp, bc_rot, cur, recA, recB, sc);
        finalize_kernel<<<1, 1, 0, stream>>>(sc, (float*)d_out);
    } else {
        // ---- Tier B (R3 verified) ----
        char* p = (char*)d_ws;
        int* counts   = (int*)p;      p += szNode;
        Scalars* sc   = (Scalars*)p;  p += szSc;
        int* offsets  = (int*)p;      p += szNode;
        int* tileSums = (int*)p;      p += szTiles;
        int* eidside  = (int*)p;

        hipMemsetAsync(counts, 0, szNode + szSc, stream);
        hist_scalars<<<egrid, 256, 0, stream>>>(conn, elem_len, elem_load, counts, sc);
        tile_sum<<<N_TILES, 256, 0, stream>>>(counts, tileSums);
        scan_tiles<<<1, 1024, 0, stream>>>(tileSums);
        scan_within<<<N_TILES, 256, 0, stream>>>(counts, tileSums, offsets);
        fill_csr<<<egrid, 256, 0, stream>>>(conn, offsets, counts, eidside);
        node_reduce_csr<<<ngrid, 256, 0, stream>>>(
            phi, grad_ux, grad_uz, grad_phi,
            prop_E, prop_A, prop_I22, elem_len, elem_dir, elem_load, conn,
            bc_disp, bc_rot, offsets, eidside, sc);
        finalize_kernel<<<1, 1, 0, stream>>>(sc, (float*)d_out);
    }
}